// Round 4
// baseline (299.805 us; speedup 1.0000x reference)
//
#include <hip/hip_runtime.h>
#include <stdint.h>

#define LOG_N 12
#define N 4096
#define NPAIR 2048
#define ROWS 2
#define NT 512

// LDS bank-deconflict swizzle: bijection on [0,4096); <=2-way bank aliasing
// (free, m136) for all 4 ownership patterns (contig, stride-8, -64, -512).
// Only touches bits 2..5, keyed on bits >=3, so every aligned 64-element
// block maps onto itself -> wave-private slices stay wave-private.
__device__ __forceinline__ int swz(int e){
  return e ^ (((e>>6)&7)<<3) ^ (((e>>3)&1)<<2);
}

// In-wave LDS ordering fence: a wave's DS ops complete in order; lgkmcnt(0)
// guarantees prior ds_writes have landed before subsequent ds_reads issue.
// No s_barrier -> no vmcnt(0) drain, twiddle prefetches stay in flight.
__device__ __forceinline__ void wave_fence(){
  asm volatile("s_waitcnt lgkmcnt(0)" ::: "memory");
  __builtin_amdgcn_sched_barrier(0);
}

// One radix-8 phase = 3 butterfly stages on the 8 register-resident elements.
// Element k of each row sits at global position base + (k << LS0).
// increasing_stride=True and nblocks=1 -> stage index == log_stride = LS0+sub.
template<int LS0>
__device__ __forceinline__ void phase3(float (&v)[ROWS][8], int base,
                                       const float4* __restrict__ twq4){
#pragma unroll
  for(int sub=0; sub<3; ++sub){
    const int ls = LS0 + sub;
    const float4* __restrict__ twq = twq4 + ls*NPAIR;
#pragma unroll
    for(int m=0;m<4;++m){
      const int k0 = (sub==0) ? (2*m) : (sub==1) ? (((m>>1)<<2)|(m&1)) : m;
      const int k1 = k0 + (1<<sub);
      const int pos0 = base + (k0<<LS0);
      // pair index p = (pos0 >> (ls+1)) * stride + (pos0 & (stride-1))
      const int p = ((pos0>>(ls+1))<<ls) | (pos0 & ((1<<ls)-1));
      const float4 q = twq[p];          // [t00 t01 t10 t11], out_i = sum_k t[i][k]*x[k]
#pragma unroll
      for(int r=0;r<ROWS;++r){
        const float x0=v[r][k0], x1=v[r][k1];
        v[r][k0] = fmaf(q.x,x0,q.y*x1);
        v[r][k1] = fmaf(q.z,x0,q.w*x1);
      }
    }
  }
}

// OCCUPANCY MODEL (measured r0-r3, 512-thr blocks on this toolchain):
//   launch_bounds 2nd arg: VGPR cap = granule8(256/arg)  [8->32, 6->40, 4->64]
//   achieved waves/SIMD = floor(256/VGPR), measured Occ ~= 0.75x theoretical
//   (m69: "waves halve at vgpr=64" -- VGPR=64 gives only 4 waves/SIMD).
// r3 at VGPR=64 ran 99us == r0's 97.5us: occupancy never improved. This
// round: ROWS=2 shrinks mandatory live state (v[2][8]=16 regs) so demand
// fits the 40-reg cap WITHOUT spill -> 6 waves/SIMD.
__global__ __launch_bounds__(NT, 6)
void butterfly_k(const float* __restrict__ x, const float* __restrict__ tw,
                 float* __restrict__ out)
{
  __shared__ float lds[ROWS*N];         // 32 KB, single-pass (both rows fit)
  const int t = threadIdx.x;
  const size_t row0 = (size_t)blockIdx.x * ROWS;
  const float4* twq4 = (const float4*)tw;

  float v[ROWS][8];

  // ---- global load, phase-A ownership: e = 8t + k (2 x dwordx4 per row)
  {
    const float4* px = (const float4*)x;
#pragma unroll
    for(int r=0;r<ROWS;++r){
      const float4 a = px[(row0+r)*(N/4) + 2*t];
      const float4 b = px[(row0+r)*(N/4) + 2*t + 1];
      v[r][0]=a.x; v[r][1]=a.y; v[r][2]=a.z; v[r][3]=a.w;
      v[r][4]=b.x; v[r][5]=b.y; v[r][6]=b.z; v[r][7]=b.w;
    }
  }

  phase3<0>(v, 8*t, twq4);              // stages 0,1,2 (strides 1,2,4)

  // ---- exchange A -> B: permutes only among 8 consecutive threads -> wave-
  // private (swz keeps aligned 64-blocks intact). No s_barrier.
  {
    const int Bb = (8*t) ^ (((t>>3)&7)<<3);   // swz'd 8-word block base
    const int flip = (t&1)<<2;
#pragma unroll
    for(int r=0;r<ROWS;++r){
      float* L = lds + r*N;
      *(float4*)(L + Bb + flip)     = make_float4(v[r][0],v[r][1],v[r][2],v[r][3]);
      *(float4*)(L + Bb + (4^flip)) = make_float4(v[r][4],v[r][5],v[r][6],v[r][7]);
    }
  }
  wave_fence();
  const int baseB = ((t>>3)<<6) | (t&7);  // e = 64*(t>>3) + (t&7) + 8k
#pragma unroll
  for(int k=0;k<8;++k){
    const int a = swz(baseB + (k<<3));
#pragma unroll
    for(int r=0;r<ROWS;++r) v[r][k] = lds[r*N + a];
  }

  phase3<3>(v, baseB, twq4);            // stages 3,4,5 (strides 8,16,32)

  // ---- exchange B -> C: permutes only among 64 consecutive threads = one
  // wave. Thread rewrites exactly the addresses it read (in-order DS pipe ->
  // reads retire before writes). No s_barrier.
#pragma unroll
  for(int k=0;k<8;++k){
    const int a = swz(baseB + (k<<3));
#pragma unroll
    for(int r=0;r<ROWS;++r) lds[r*N + a] = v[r][k];
  }
  wave_fence();
  const int baseC = ((t>>6)<<9) | (t&63); // e = 512*(t>>6) + (t&63) + 64k
#pragma unroll
  for(int k=0;k<8;++k){
    const int a = swz(baseC + (k<<6));
#pragma unroll
    for(int r=0;r<ROWS;++r) v[r][k] = lds[r*N + a];
  }

  phase3<6>(v, baseC, twq4);            // stages 6,7,8 (strides 64,128,256)

  // ---- exchange C -> D: crosses waves -> the kernel's ONE s_barrier.
  // C-order writes hit the same wave-private addresses just read.
#pragma unroll
  for(int k=0;k<8;++k){
    const int a = swz(baseC + (k<<6));
#pragma unroll
    for(int r=0;r<ROWS;++r) lds[r*N + a] = v[r][k];
  }
  __syncthreads();
  // e = t + 512k
#pragma unroll
  for(int k=0;k<8;++k){
    const int a = swz(t + (k<<9));
#pragma unroll
    for(int r=0;r<ROWS;++r) v[r][k] = lds[r*N + a];
  }

  phase3<9>(v, t, twq4);                // stages 9,10,11 (strides 512,1024,2048)

  // ---- store: element t + 512k of each row; lanes consecutive -> coalesced
#pragma unroll
  for(int r=0;r<ROWS;++r){
    float* po = out + (row0+r)*N + t;
#pragma unroll
    for(int k=0;k<8;++k) po[(size_t)(k<<9)] = v[r][k];
  }
}

extern "C" void kernel_launch(void* const* d_in, const int* in_sizes, int n_in,
                              void* d_out, int out_size, void* d_ws, size_t ws_size,
                              hipStream_t stream) {
  const float* x  = (const float*)d_in[0];   // (8192, 4096) fp32
  const float* tw = (const float*)d_in[1];   // (1,1,12,2048,2,2) fp32
  float* out = (float*)d_out;                // (8192, 4096) fp32
  const int batch = in_sizes[0] / N;         // 8192
  dim3 grid(batch / ROWS), block(NT);
  hipLaunchKernelGGL(butterfly_k, grid, block, 0, stream, x, tw, out);
}

// Round 5
// 251.437 us; speedup vs baseline: 1.1924x; 1.1924x over previous
//
#include <hip/hip_runtime.h>
#include <stdint.h>

#define LOG_N 12
#define N 4096
#define NPAIR 2048
#define ROWS 4
#define NT 512
#define TWA_QUADS (12*512)   // reorganized phase-A twiddles: 96 KB in d_ws

// LDS bank-deconflict swizzle: bijection on [0,4096); <=2-way bank aliasing
// for all 4 ownership patterns (contig, stride-8, -64, -512). Only touches
// bits 2..5, keyed on bits >=3 -> aligned 64-blocks map onto themselves, so
// wave-private slices stay wave-private.
__device__ __forceinline__ int swz(int e){
  return e ^ (((e>>6)&7)<<3) ^ (((e>>3)&1)<<2);
}

// In-wave LDS ordering fence (no s_barrier -> no vmcnt(0) drain).
__device__ __forceinline__ void wave_fence(){
  asm volatile("s_waitcnt lgkmcnt(0)" ::: "memory");
  __builtin_amdgcn_sched_barrier(0);
}

// ---- Preprocess: transpose phase-A twiddles so thread t's m-th quad of
// stage ls sits at twA[(ls*4+m)*512 + t] (lane-stride 16 B -> coalesced).
// Original need: all three stages 0..2 use quad p = 4t+m of their slice
// (verified: ls=0,1,2 all reduce to p = 4t+m under the k0 patterns).
// TA theory (r0-r4): the original access is lane-stride 64 B -> 64 cache
// lines per instruction -> 768 of ~1400 per-wave L1 line-passes; this pipe,
// not occupancy, is the saturated resource (r4: Occ 80%, dur WORSE).
__global__ void reorg_twA(const float4* __restrict__ tw, float4* __restrict__ twA){
  const int b = blockIdx.x;      // b = ls*4+m, 12 blocks
  const int t = threadIdx.x;     // 512 threads
  const int ls = b >> 2, m = b & 3;
  twA[b*NT + t] = tw[ls*NPAIR + 4*t + m];
}

// Phase A (stages 0,1,2) from reorganized twiddles: coalesced loads.
__device__ __forceinline__ void phaseA(float (&v)[ROWS][8], int t,
                                       const float4* __restrict__ twA){
#pragma unroll
  for(int sub=0; sub<3; ++sub){
#pragma unroll
    for(int m=0;m<4;++m){
      const int k0 = (sub==0) ? (2*m) : (sub==1) ? (((m>>1)<<2)|(m&1)) : m;
      const int k1 = k0 + (1<<sub);
      const float4 q = twA[(sub*4+m)*NT + t];
#pragma unroll
      for(int r=0;r<ROWS;++r){
        const float x0=v[r][k0], x1=v[r][k1];
        v[r][k0] = fmaf(q.x,x0,q.y*x1);
        v[r][k1] = fmaf(q.z,x0,q.w*x1);
      }
    }
  }
}

// One radix-8 phase = 3 butterfly stages; element k of each row is at
// global position base + (k << LS0). Used for LS0 = 3,6,9 (those access
// patterns are already lane-contiguous: 16 lines/instr, minimum for f4).
template<int LS0>
__device__ __forceinline__ void phase3(float (&v)[ROWS][8], int base,
                                       const float4* __restrict__ twq4){
#pragma unroll
  for(int sub=0; sub<3; ++sub){
    const int ls = LS0 + sub;
    const float4* __restrict__ twq = twq4 + ls*NPAIR;
#pragma unroll
    for(int m=0;m<4;++m){
      const int k0 = (sub==0) ? (2*m) : (sub==1) ? (((m>>1)<<2)|(m&1)) : m;
      const int k1 = k0 + (1<<sub);
      const int pos0 = base + (k0<<LS0);
      const int p = ((pos0>>(ls+1))<<ls) | (pos0 & ((1<<ls)-1));
      const float4 q = twq[p];
#pragma unroll
      for(int r=0;r<ROWS;++r){
        const float x0=v[r][k0], x1=v[r][k1];
        v[r][k0] = fmaf(q.x,x0,q.y*x1);
        v[r][k1] = fmaf(q.z,x0,q.w*x1);
      }
    }
  }
}

// launch_bounds(512,4): measured cap 64 VGPR, no spill (r3). ROWS=4 for best
// twiddle amortization (1.5 loads/elem); r4 proved occupancy isn't the lever.
template<bool RG>
__global__ __launch_bounds__(NT, 4)
void butterfly_k(const float* __restrict__ x, const float* __restrict__ tw,
                 const float4* __restrict__ twA, float* __restrict__ out)
{
  __shared__ float lds[2*N];            // 32 KB, pair-pumped exchanges
  const int t = threadIdx.x;
  const size_t row0 = (size_t)blockIdx.x * ROWS;
  const float4* twq4 = (const float4*)tw;

  float v[ROWS][8];

  // ---- global load, phase-A ownership: e = 8t + k (2 x dwordx4 per row)
  {
    const float4* px = (const float4*)x;
#pragma unroll
    for(int r=0;r<ROWS;++r){
      const float4 a = px[(row0+r)*(N/4) + 2*t];
      const float4 b = px[(row0+r)*(N/4) + 2*t + 1];
      v[r][0]=a.x; v[r][1]=a.y; v[r][2]=a.z; v[r][3]=a.w;
      v[r][4]=b.x; v[r][5]=b.y; v[r][6]=b.z; v[r][7]=b.w;
    }
  }

  if (RG) phaseA(v, t, twA);            // stages 0,1,2 — coalesced twiddles
  else    phase3<0>(v, 8*t, twq4);      // fallback (no workspace)

  const int baseB = ((t>>3)<<6) | (t&7);
  // ---- exchange A -> B: wave-private (8-thread groups), no s_barrier.
  {
    const int Bb = (8*t) ^ (((t>>3)&7)<<3);
    const int flip = (t&1)<<2;
#pragma unroll
    for(int pp=0;pp<2;++pp){
      wave_fence();                     // pp=1: pair-0 reads retired first
#pragma unroll
      for(int rr=0;rr<2;++rr){
        float* L = lds + rr*N;
        const int r = 2*pp + rr;
        *(float4*)(L + Bb + flip)     = make_float4(v[r][0],v[r][1],v[r][2],v[r][3]);
        *(float4*)(L + Bb + (4^flip)) = make_float4(v[r][4],v[r][5],v[r][6],v[r][7]);
      }
      wave_fence();
#pragma unroll
      for(int k=0;k<8;++k){
        const int a = swz(baseB + (k<<3));
#pragma unroll
        for(int rr=0;rr<2;++rr) v[2*pp+rr][k] = lds[rr*N + a];
      }
    }
  }

  phase3<3>(v, baseB, twq4);            // stages 3,4,5 (strides 8,16,32)

  const int baseC = ((t>>6)<<9) | (t&63);
  // ---- exchange B -> C: wave-private (64-thread groups), no s_barrier.
#pragma unroll
  for(int pp=0;pp<2;++pp){
    wave_fence();
#pragma unroll
    for(int k=0;k<8;++k){
      const int a = swz(baseB + (k<<3));
#pragma unroll
      for(int rr=0;rr<2;++rr) lds[rr*N + a] = v[2*pp+rr][k];
    }
    wave_fence();
#pragma unroll
    for(int k=0;k<8;++k){
      const int a = swz(baseC + (k<<6));
#pragma unroll
      for(int rr=0;rr<2;++rr) v[2*pp+rr][k] = lds[rr*N + a];
    }
  }

  phase3<6>(v, baseC, twq4);            // stages 6,7,8 (strides 64,128,256)

  // ---- exchange C -> D: crosses waves. Rows {0,1} then {2,3}.
  wave_fence();
#pragma unroll
  for(int k=0;k<8;++k){
    const int a = swz(baseC + (k<<6));
#pragma unroll
    for(int rr=0;rr<2;++rr) lds[rr*N + a] = v[rr][k];
  }
  __syncthreads();
#pragma unroll
  for(int k=0;k<8;++k){
    const int a = swz(t + (k<<9));
#pragma unroll
    for(int rr=0;rr<2;++rr) v[rr][k] = lds[rr*N + a];
  }
  __syncthreads();                      // all pair-0 reads done before clobber
#pragma unroll
  for(int k=0;k<8;++k){
    const int a = swz(baseC + (k<<6));
#pragma unroll
    for(int rr=0;rr<2;++rr) lds[rr*N + a] = v[2+rr][k];
  }
  __syncthreads();
#pragma unroll
  for(int k=0;k<8;++k){
    const int a = swz(t + (k<<9));
#pragma unroll
    for(int rr=0;rr<2;++rr) v[2+rr][k] = lds[rr*N + a];
  }

  phase3<9>(v, t, twq4);                // stages 9,10,11 (strides 512,1024,2048)

  // ---- store: element t + 512k of each row; lanes consecutive -> coalesced
#pragma unroll
  for(int r=0;r<ROWS;++r){
    float* po = out + (row0+r)*N + t;
#pragma unroll
    for(int k=0;k<8;++k) po[(size_t)(k<<9)] = v[r][k];
  }
}

extern "C" void kernel_launch(void* const* d_in, const int* in_sizes, int n_in,
                              void* d_out, int out_size, void* d_ws, size_t ws_size,
                              hipStream_t stream) {
  const float* x  = (const float*)d_in[0];   // (8192, 4096) fp32
  const float* tw = (const float*)d_in[1];   // (1,1,12,2048,2,2) fp32
  float* out = (float*)d_out;                // (8192, 4096) fp32
  const int batch = in_sizes[0] / N;         // 8192
  dim3 grid(batch / ROWS), block(NT);

  if (d_ws && ws_size >= TWA_QUADS*sizeof(float4)) {
    hipLaunchKernelGGL(reorg_twA, dim3(12), dim3(NT), 0, stream,
                       (const float4*)tw, (float4*)d_ws);
    hipLaunchKernelGGL((butterfly_k<true>), grid, block, 0, stream,
                       x, tw, (const float4*)d_ws, out);
  } else {
    hipLaunchKernelGGL((butterfly_k<false>), grid, block, 0, stream,
                       x, tw, (const float4*)nullptr, out);
  }
}